// Round 8
// baseline (195.628 us; speedup 1.0000x reference)
//
#include <hip/hip_runtime.h>

#define B_ 4
#define S_ 2048
#define HIDN 512
#define NH 8
#define DH 64

typedef __attribute__((ext_vector_type(8))) short short8;
typedef __attribute__((ext_vector_type(4))) short short4v;
typedef __attribute__((ext_vector_type(8))) __bf16 bf16x8;
typedef __attribute__((ext_vector_type(4))) float floatx4;
typedef __attribute__((ext_vector_type(2))) unsigned uint2v;
typedef __attribute__((ext_vector_type(4))) unsigned uint4v;

__device__ inline short f2bf(float f) {            // RTNE
    union { float f; unsigned u; } x; x.f = f;
    unsigned r = x.u + 0x7fffu + ((x.u >> 16) & 1u);
    return (short)(r >> 16);
}

// pack two floats -> two bf16 (round-half-up) in one uint via v_perm
__device__ inline unsigned pack2(float a, float b) {
    unsigned ua = __builtin_bit_cast(unsigned, a) + 0x8000u;
    unsigned ub = __builtin_bit_cast(unsigned, b) + 0x8000u;
    return __builtin_amdgcn_perm(ub, ua, 0x07060302);  // shorts [a, b]
}

__device__ inline short8 cvt8(const float* __restrict__ p) {
    floatx4 f0 = *(const floatx4*)p;
    floatx4 f1 = *(const floatx4*)(p + 4);
    short8 r;
    r[0] = f2bf(f0[0]); r[1] = f2bf(f0[1]); r[2] = f2bf(f0[2]); r[3] = f2bf(f0[3]);
    r[4] = f2bf(f1[0]); r[5] = f2bf(f1[1]); r[6] = f2bf(f1[2]); r[7] = f2bf(f1[3]);
    return r;
}

__device__ inline floatx4 mfma_s(short8 a, short8 b, floatx4 c) {
    return __builtin_amdgcn_mfma_f32_16x16x32_bf16(
        __builtin_bit_cast(bf16x8, a), __builtin_bit_cast(bf16x8, b), c, 0, 0, 0);
}

__device__ inline float vmax4(floatx4 v) {
    return fmaxf(fmaxf(v[0], v[1]), fmaxf(v[2], v[3]));
}

// ---------------------------------------------------------------------------
// Pre-convert Wq,Wk,Wv (fp32 -> bf16). grid (256,3) x 256 thr, 4 elem/thr.
// (round-4 verbatim, known good)
// ---------------------------------------------------------------------------
__global__ void cvt_w(const float* __restrict__ wq, const float* __restrict__ wk,
                      const float* __restrict__ wv, short* __restrict__ out) {
    const float* src = blockIdx.y == 0 ? wq : (blockIdx.y == 1 ? wk : wv);
    int i = (blockIdx.x * 256 + threadIdx.x) * 4;
    floatx4 f = *(const floatx4*)&src[i];
    short4v v; v[0]=f2bf(f[0]); v[1]=f2bf(f[1]); v[2]=f2bf(f[2]); v[3]=f2bf(f[3]);
    *(short4v*)&out[blockIdx.y * (HIDN * HIDN) + i] = v;
}

// ---------------------------------------------------------------------------
// Fused QKV projection (round-4 verbatim, known good). grid (64,4,3).
// z=0:Q, z=1:K (head layout), z=2:V^T. 128x128 tile, BK=32, padded LDS.
// ---------------------------------------------------------------------------
__global__ __launch_bounds__(256) void gemm_qkv(const float* __restrict__ xq,
                                                const float* __restrict__ xk,
                                                const float* __restrict__ xv,
                                                const short* __restrict__ wb,
                                                short* __restrict__ Qh,
                                                short* __restrict__ Kh,
                                                short* __restrict__ VT) {
    const int z = blockIdx.z;
    const float* X = z == 0 ? xq : (z == 1 ? xk : xv);
    const short* W = wb + z * (HIDN * HIDN);
    short* dstQK = z == 0 ? Qh : Kh;

    __shared__ __align__(16) short Als[128][40];
    __shared__ __align__(16) short Bls[128][40];

    const int t = threadIdx.x;
    const int w = t >> 6, lane = t & 63, quad = lane >> 4, l16 = lane & 15;
    const int wm = (w & 1) * 64, wn = (w >> 1) * 64;
    const int m0 = blockIdx.x * 128, n0 = blockIdx.y * 128;

    floatx4 acc[4][4];
    floatx4 zero = {0.f, 0.f, 0.f, 0.f};
#pragma unroll
    for (int i = 0; i < 4; i++)
#pragma unroll
        for (int j = 0; j < 4; j++) acc[i][j] = zero;

    const int row0 = t >> 2, c8 = (t & 3) * 8;

    for (int k0 = 0; k0 < HIDN; k0 += 32) {
        __syncthreads();
        *(short8*)&Als[row0][c8]    = cvt8(&X[(m0 + row0) * HIDN + k0 + c8]);
        *(short8*)&Als[row0+64][c8] = cvt8(&X[(m0 + row0 + 64) * HIDN + k0 + c8]);
        *(short8*)&Bls[row0][c8]    = *(const short8*)&W[(n0 + row0) * HIDN + k0 + c8];
        *(short8*)&Bls[row0+64][c8] = *(const short8*)&W[(n0 + row0 + 64) * HIDN + k0 + c8];
        __syncthreads();

        short8 a[4], b[4];
#pragma unroll
        for (int i = 0; i < 4; i++) a[i] = *(const short8*)&Als[wm + i*16 + l16][quad*8];
#pragma unroll
        for (int j = 0; j < 4; j++) b[j] = *(const short8*)&Bls[wn + j*16 + l16][quad*8];
#pragma unroll
        for (int i = 0; i < 4; i++)
#pragma unroll
            for (int j = 0; j < 4; j++)
                acc[i][j] = mfma_s(a[i], b[j], acc[i][j]);
    }

    if (z < 2) {   // head layout (B,NH,S,DH)
#pragma unroll
        for (int i = 0; i < 4; i++)
#pragma unroll
            for (int j = 0; j < 4; j++)
#pragma unroll
                for (int r = 0; r < 4; r++) {
                    int m = m0 + wm + i*16 + quad*4 + r;
                    int n = n0 + wn + j*16 + l16;
                    int bb = m >> 11, s = m & 2047, h = n >> 6, d = n & 63;
                    dstQK[((bb * NH + h) * S_ + s) * DH + d] = f2bf(acc[i][j][r]);
                }
    } else {       // V^T (B,NH,DH,S)
#pragma unroll
        for (int i = 0; i < 4; i++)
#pragma unroll
            for (int j = 0; j < 4; j++) {
                int s0 = m0 + wm + i*16 + quad*4;
                int n = n0 + wn + j*16 + l16;
                int bb = s0 >> 11, s = s0 & 2047, h = n >> 6, d = n & 63;
                uint2v v;
                v[0] = pack2(acc[i][j][0], acc[i][j][1]);
                v[1] = pack2(acc[i][j][2], acc[i][j][3]);
                *(uint2v*)&VT[((bb * NH + h) * DH + d) * S_ + s] = v;
            }
    }
}

// ---------------------------------------------------------------------------
// Out projection (round-4 verbatim, known good). 128x64 tile, grid(64,8),
// BK=32 padded LDS. AO bf16, Wo fp32 cvt in staging, out fp32.
// ---------------------------------------------------------------------------
__global__ __launch_bounds__(256) void gemm_out(const short* __restrict__ AO,
                                                const float* __restrict__ Wo,
                                                float* __restrict__ C) {
    __shared__ __align__(16) short Als[128][40];
    __shared__ __align__(16) short Bls[64][40];

    const int t = threadIdx.x;
    const int w = t >> 6, lane = t & 63, quad = lane >> 4, l16 = lane & 15;
    const int wm = (w & 1) * 64, wn = (w >> 1) * 32;
    const int m0 = blockIdx.x * 128, n0 = blockIdx.y * 64;

    floatx4 acc[4][2];
    floatx4 zero = {0.f, 0.f, 0.f, 0.f};
#pragma unroll
    for (int i = 0; i < 4; i++)
#pragma unroll
        for (int j = 0; j < 2; j++) acc[i][j] = zero;

    const int row0 = t >> 2, c8 = (t & 3) * 8;

    for (int k0 = 0; k0 < HIDN; k0 += 32) {
        __syncthreads();
        *(short8*)&Als[row0][c8]    = *(const short8*)&AO[(m0 + row0) * HIDN + k0 + c8];
        *(short8*)&Als[row0+64][c8] = *(const short8*)&AO[(m0 + row0 + 64) * HIDN + k0 + c8];
        if (row0 < 64)
            *(short8*)&Bls[row0][c8] = cvt8(&Wo[(n0 + row0) * HIDN + k0 + c8]);
        __syncthreads();

        short8 a[4], b[2];
#pragma unroll
        for (int i = 0; i < 4; i++) a[i] = *(const short8*)&Als[wm + i*16 + l16][quad*8];
#pragma unroll
        for (int j = 0; j < 2; j++) b[j] = *(const short8*)&Bls[wn + j*16 + l16][quad*8];
#pragma unroll
        for (int i = 0; i < 4; i++)
#pragma unroll
            for (int j = 0; j < 2; j++)
                acc[i][j] = mfma_s(a[i], b[j], acc[i][j]);
    }

#pragma unroll
    for (int i = 0; i < 4; i++)
#pragma unroll
        for (int j = 0; j < 2; j++)
#pragma unroll
            for (int r = 0; r < 4; r++) {
                int m = m0 + wm + i*16 + quad*4 + r;
                int n = n0 + wn + j*16 + l16;
                C[m * HIDN + n] = acc[i][j][r];
            }
}

// ---------------------------------------------------------------------------
// Flash attention (round-7 version UNDER TEST). Transposed orientation,
// chunked conflict-free LDS, register-shuffle P, 2 barriers/tile.
// ---------------------------------------------------------------------------
__global__ __launch_bounds__(256, 4) void attn_kernel(const short* __restrict__ Qh,
                                                      const short* __restrict__ Kh,
                                                      const short* __restrict__ VT,
                                                      const int* __restrict__ vlen,
                                                      short* __restrict__ AO) {
    __shared__ __align__(16) short Ksh[128 * 64];   // [c 0..7][key 0..127] x8
    __shared__ __align__(16) short Vsh[64 * 128];   // [cq 0..15][d 0..63]  x8

    const int t = threadIdx.x, w = t >> 6, lane = t & 63;
    const int quad = lane >> 4, l16 = lane & 15;
    const int qb = blockIdx.x * 64;
    const int h = blockIdx.y, b = blockIdx.z;
    const int bh = b * NH + h;
    const int vl = vlen[b];
    const int nt = (vl + 127) >> 7;

    const float SC = 0.180336879f;                   // 0.125 * log2(e)

    const short* qrow = &Qh[(bh * S_ + qb + w * 16 + l16) * DH];
    short8 qa0 = *(const short8*)&qrow[quad * 8];
    short8 qa1 = *(const short8*)&qrow[32 + quad * 8];

    float m_run = -1e30f, l_run = 0.f;
    floatx4 Oacc[4];
    floatx4 zero = {0.f, 0.f, 0.f, 0.f};
#pragma unroll
    for (int dt = 0; dt < 4; dt++) Oacc[dt] = zero;

    const int src  = ((quad & 1) << 5) + l16;
    const int src2 = src + 16;
    const bool hi = (quad & 2) != 0;

    for (int kt = 0; kt < nt; kt++) {
        const int base = kt << 7;
        const bool bnd = (base + 128) > vl;
        __syncthreads();
        {
            const short* Kg = &Kh[(bh * S_ + base) * DH];
            const short* Vg = &VT[bh * DH * S_ + base];
#pragma unroll
            for (int r = 0; r < 4; r++) {
                int slot = r * 256 + t;
                int c = slot >> 7, key = slot & 127;
                *(short8*)&Ksh[slot * 8] = *(const short8*)&Kg[key * DH + c * 8];
            }
#pragma unroll
            for (int r = 0; r < 4; r++) {
                int slot = r * 256 + t;
                int cq = slot >> 6, d = slot & 63;
                *(short8*)&Vsh[slot * 8] =
                    *(const short8*)&Vg[d * S_ + (cq >> 2) * 32 + (cq & 3) * 8];
            }
        }
        __syncthreads();

        floatx4 sc[8];
#pragma unroll
        for (int n = 0; n < 8; n++) {
            int key = n * 16 + l16;
            short8 kb0 = *(const short8*)&Ksh[(quad * 128 + key) * 8];
            short8 kb1 = *(const short8*)&Ksh[((4 + quad) * 128 + key) * 8];
            floatx4 s = zero;
            s = mfma_s(kb0, qa0, s);
            s = mfma_s(kb1, qa1, s);
            sc[n] = s;
        }

        if (!bnd) {
#pragma unroll
            for (int n = 0; n < 8; n++)
#pragma unroll
                for (int r = 0; r < 4; r++) sc[n][r] *= SC;
        } else {
#pragma unroll
            for (int n = 0; n < 8; n++)
#pragma unroll
                for (int r = 0; r < 4; r++) {
                    int key = base + n * 16 + quad * 4 + r;
                    sc[n][r] = (key < vl) ? sc[n][r] * SC : -1e30f;
                }
        }

        float mx = vmax4(sc[0]);
#pragma unroll
        for (int n = 1; n < 8; n++) mx = fmaxf(mx, vmax4(sc[n]));
        mx = fmaxf(mx, __shfl_xor(mx, 16));
        mx = fmaxf(mx, __shfl_xor(mx, 32));
        float mnew = fmaxf(m_run, mx);
        float alpha = __builtin_amdgcn_exp2f(m_run - mnew);
        m_run = mnew;
        float rs = 0.f;
#pragma unroll
        for (int n = 0; n < 8; n++)
#pragma unroll
            for (int r = 0; r < 4; r++) {
                float p = __builtin_amdgcn_exp2f(sc[n][r] - mnew);
                sc[n][r] = p;
                rs += p;
            }
        rs += __shfl_xor(rs, 16);
        rs += __shfl_xor(rs, 32);
        l_run = l_run * alpha + rs;
#pragma unroll
        for (int dt = 0; dt < 4; dt++)
#pragma unroll
            for (int r = 0; r < 4; r++) Oacc[dt][r] *= alpha;

        unsigned pu0[8], pu1[8];
#pragma unroll
        for (int n = 0; n < 8; n++) {
            pu0[n] = pack2(sc[n][0], sc[n][1]);
            pu1[n] = pack2(sc[n][2], sc[n][3]);
        }

#pragma unroll
        for (int kk = 0; kk < 4; kk++) {
            unsigned a0 = (unsigned)__shfl((int)pu0[2 * kk], src);
            unsigned a1 = (unsigned)__shfl((int)pu1[2 * kk], src);
            unsigned a2 = (unsigned)__shfl((int)pu0[2 * kk], src2);
            unsigned a3 = (unsigned)__shfl((int)pu1[2 * kk], src2);
            unsigned b0 = (unsigned)__shfl((int)pu0[2 * kk + 1], src);
            unsigned b1 = (unsigned)__shfl((int)pu1[2 * kk + 1], src);
            unsigned b2 = (unsigned)__shfl((int)pu0[2 * kk + 1], src2);
            unsigned b3 = (unsigned)__shfl((int)pu1[2 * kk + 1], src2);
            uint4v pf;
            pf[0] = hi ? b0 : a0; pf[1] = hi ? b1 : a1;
            pf[2] = hi ? b2 : a2; pf[3] = hi ? b3 : a3;
            short8 pfs = __builtin_bit_cast(short8, pf);
#pragma unroll
            for (int dt = 0; dt < 4; dt++) {
                short8 vf = *(const short8*)&Vsh[((kk * 4 + quad) * 64 + dt * 16 + l16) * 8];
                Oacc[dt] = mfma_s(vf, pfs, Oacc[dt]);
            }
        }
    }

    float inv = 1.0f / l_run;
    int q = qb + w * 16 + l16;
    short* dst = &AO[(b * S_ + q) * HIDN + h * DH];
#pragma unroll
    for (int dt = 0; dt < 4; dt++) {
        uint2v v;
        v[0] = pack2(Oacc[dt][0] * inv, Oacc[dt][1] * inv);
        v[1] = pack2(Oacc[dt][2] * inv, Oacc[dt][3] * inv);
        *(uint2v*)&dst[dt * 16 + quad * 4] = v;
    }
}

extern "C" void kernel_launch(void* const* d_in, const int* in_sizes, int n_in,
                              void* d_out, int out_size, void* d_ws, size_t ws_size,
                              hipStream_t stream) {
    const float* q  = (const float*)d_in[0];
    const float* k  = (const float*)d_in[1];
    const float* v  = (const float*)d_in[2];
    const int*   vl = (const int*)d_in[3];
    const float* wq = (const float*)d_in[4];
    const float* wk = (const float*)d_in[5];
    const float* wv = (const float*)d_in[6];
    const float* wo = (const float*)d_in[7];
    float* out = (float*)d_out;

    const size_t HSZ = (size_t)B_ * NH * S_ * DH;  // 4.19M shorts
    short* Qh  = (short*)d_ws;
    short* Kh  = Qh + HSZ;
    short* VT  = Kh + HSZ;
    short* AO  = VT + HSZ;
    short* Wqkv = AO;   // 3*256K shorts in the AO region (dead until attn)

    dim3 blk(256);
    cvt_w<<<dim3(256, 3), blk, 0, stream>>>(wq, wk, wv, Wqkv);
    gemm_qkv<<<dim3(64, 4, 3), blk, 0, stream>>>(q, k, v, Wqkv, Qh, Kh, VT);
    attn_kernel<<<dim3(S_ / 64, NH, B_), blk, 0, stream>>>(Qh, Kh, VT, vl, AO);
    gemm_out<<<dim3(64, 8), blk, 0, stream>>>(AO, wo, out);
}

// Round 9
// 178.618 us; speedup vs baseline: 1.0952x; 1.0952x over previous
//
#include <hip/hip_runtime.h>

#define B_ 4
#define S_ 2048
#define HIDN 512
#define NH 8
#define DH 64

typedef __attribute__((ext_vector_type(8))) short short8;
typedef __attribute__((ext_vector_type(4))) short short4v;
typedef __attribute__((ext_vector_type(8))) __bf16 bf16x8;
typedef __attribute__((ext_vector_type(4))) float floatx4;
typedef __attribute__((ext_vector_type(2))) unsigned uint2v;
typedef __attribute__((ext_vector_type(4))) unsigned uint4v;

__device__ inline short f2bf(float f) {            // RTNE
    union { float f; unsigned u; } x; x.f = f;
    unsigned r = x.u + 0x7fffu + ((x.u >> 16) & 1u);
    return (short)(r >> 16);
}

// pack two floats -> two bf16 (round-half-up) in one uint via v_perm
__device__ inline unsigned pack2(float a, float b) {
    unsigned ua = __builtin_bit_cast(unsigned, a) + 0x8000u;
    unsigned ub = __builtin_bit_cast(unsigned, b) + 0x8000u;
    return __builtin_amdgcn_perm(ub, ua, 0x07060302);  // shorts [a, b]
}

// 8 fp32 -> 8 bf16 (12 VALU)
__device__ inline short8 cvt8(const float* __restrict__ p) {
    floatx4 f0 = *(const floatx4*)p;
    floatx4 f1 = *(const floatx4*)(p + 4);
    uint4v u;
    u[0] = pack2(f0[0], f0[1]); u[1] = pack2(f0[2], f0[3]);
    u[2] = pack2(f1[0], f1[1]); u[3] = pack2(f1[2], f1[3]);
    return __builtin_bit_cast(short8, u);
}

__device__ inline floatx4 mfma_s(short8 a, short8 b, floatx4 c) {
    return __builtin_amdgcn_mfma_f32_16x16x32_bf16(
        __builtin_bit_cast(bf16x8, a), __builtin_bit_cast(bf16x8, b), c, 0, 0, 0);
}

__device__ inline float vmax4(floatx4 v) {
    return fmaxf(fmaxf(v[0], v[1]), fmaxf(v[2], v[3]));
}

// ---------------------------------------------------------------------------
// Pre-convert Wq,Wk,Wv (fp32 -> bf16). grid (256,3) x 256 thr, 4 elem/thr.
// ---------------------------------------------------------------------------
__global__ void cvt_w(const float* __restrict__ wq, const float* __restrict__ wk,
                      const float* __restrict__ wv, short* __restrict__ out) {
    const float* src = blockIdx.y == 0 ? wq : (blockIdx.y == 1 ? wk : wv);
    int i = (blockIdx.x * 256 + threadIdx.x) * 4;
    floatx4 f = *(const floatx4*)&src[i];
    short4v v; v[0]=f2bf(f[0]); v[1]=f2bf(f[1]); v[2]=f2bf(f[2]); v[3]=f2bf(f[3]);
    *(short4v*)&out[blockIdx.y * (HIDN * HIDN) + i] = v;
}

// ---------------------------------------------------------------------------
// Fused QKV projection. grid (64,4,3); z=0:Q, z=1:K (head layout), z=2:V^T.
// r4 2D-padded idiom, BK=64 (8 k-iters). X fp32 cvt in staging; W bf16.
// ---------------------------------------------------------------------------
__global__ __launch_bounds__(256) void gemm_qkv(const float* __restrict__ xq,
                                                const float* __restrict__ xk,
                                                const float* __restrict__ xv,
                                                const short* __restrict__ wb,
                                                short* __restrict__ Qh,
                                                short* __restrict__ Kh,
                                                short* __restrict__ VT) {
    const int z = blockIdx.z;
    const float* X = z == 0 ? xq : (z == 1 ? xk : xv);
    const short* W = wb + z * (HIDN * HIDN);
    short* dstQK = z == 0 ? Qh : Kh;

    __shared__ __align__(16) short Als[128][72];   // 64 cols + pad to 72
    __shared__ __align__(16) short Bls[128][72];

    const int t = threadIdx.x;
    const int w = t >> 6, lane = t & 63, quad = lane >> 4, l16 = lane & 15;
    const int wm = (w & 1) * 64, wn = (w >> 1) * 64;
    const int m0 = blockIdx.x * 128, n0 = blockIdx.y * 128;

    floatx4 acc[4][4];
    floatx4 zero = {0.f, 0.f, 0.f, 0.f};
#pragma unroll
    for (int i = 0; i < 4; i++)
#pragma unroll
        for (int j = 0; j < 4; j++) acc[i][j] = zero;

    const int row0 = t >> 3;        // 0..31
    const int c8 = (t & 7) * 8;     // 0..56

    for (int k0 = 0; k0 < HIDN; k0 += 64) {
        __syncthreads();
#pragma unroll
        for (int rr = 0; rr < 4; rr++)
            *(short8*)&Als[row0 + rr*32][c8] =
                cvt8(&X[(m0 + row0 + rr*32) * HIDN + k0 + c8]);
#pragma unroll
        for (int rr = 0; rr < 4; rr++)
            *(short8*)&Bls[row0 + rr*32][c8] =
                *(const short8*)&W[(n0 + row0 + rr*32) * HIDN + k0 + c8];
        __syncthreads();

#pragma unroll
        for (int ks = 0; ks < 2; ks++) {
            const int cq8 = (ks * 4 + quad) * 8;
            short8 a[4], b[4];
#pragma unroll
            for (int i = 0; i < 4; i++)
                a[i] = *(const short8*)&Als[wm + i*16 + l16][cq8];
#pragma unroll
            for (int j = 0; j < 4; j++)
                b[j] = *(const short8*)&Bls[wn + j*16 + l16][cq8];
#pragma unroll
            for (int i = 0; i < 4; i++)
#pragma unroll
                for (int j = 0; j < 4; j++)
                    acc[i][j] = mfma_s(a[i], b[j], acc[i][j]);
        }
    }

    if (z < 2) {   // head layout (B,NH,S,DH)
#pragma unroll
        for (int i = 0; i < 4; i++)
#pragma unroll
            for (int j = 0; j < 4; j++)
#pragma unroll
                for (int r = 0; r < 4; r++) {
                    int m = m0 + wm + i*16 + quad*4 + r;
                    int n = n0 + wn + j*16 + l16;
                    int bb = m >> 11, s = m & 2047, h = n >> 6, d = n & 63;
                    dstQK[((bb * NH + h) * S_ + s) * DH + d] = f2bf(acc[i][j][r]);
                }
    } else {       // V^T (B,NH,DH,S)
#pragma unroll
        for (int i = 0; i < 4; i++)
#pragma unroll
            for (int j = 0; j < 4; j++) {
                int s0 = m0 + wm + i*16 + quad*4;
                int n = n0 + wn + j*16 + l16;
                int bb = s0 >> 11, s = s0 & 2047, h = n >> 6, d = n & 63;
                uint2v v;
                v[0] = pack2(acc[i][j][0], acc[i][j][1]);
                v[1] = pack2(acc[i][j][2], acc[i][j][3]);
                *(uint2v*)&VT[((bb * NH + h) * DH + d) * S_ + s] = v;
            }
    }
}

// ---------------------------------------------------------------------------
// Out projection. 128x64 tile, grid(64,8), BK=64 padded. AO bf16, Wo fp32
// cvt in staging, out fp32.
// ---------------------------------------------------------------------------
__global__ __launch_bounds__(256) void gemm_out(const short* __restrict__ AO,
                                                const float* __restrict__ Wo,
                                                float* __restrict__ C) {
    __shared__ __align__(16) short Als[128][72];
    __shared__ __align__(16) short Bls[64][72];

    const int t = threadIdx.x;
    const int w = t >> 6, lane = t & 63, quad = lane >> 4, l16 = lane & 15;
    const int wm = (w & 1) * 64, wn = (w >> 1) * 32;
    const int m0 = blockIdx.x * 128, n0 = blockIdx.y * 64;

    floatx4 acc[4][2];
    floatx4 zero = {0.f, 0.f, 0.f, 0.f};
#pragma unroll
    for (int i = 0; i < 4; i++)
#pragma unroll
        for (int j = 0; j < 2; j++) acc[i][j] = zero;

    const int row0 = t >> 3;        // 0..31
    const int c8 = (t & 7) * 8;     // 0..56

    for (int k0 = 0; k0 < HIDN; k0 += 64) {
        __syncthreads();
#pragma unroll
        for (int rr = 0; rr < 4; rr++)
            *(short8*)&Als[row0 + rr*32][c8] =
                *(const short8*)&AO[(m0 + row0 + rr*32) * HIDN + k0 + c8];
#pragma unroll
        for (int rr = 0; rr < 2; rr++)
            *(short8*)&Bls[row0 + rr*32][c8] =
                cvt8(&Wo[(n0 + row0 + rr*32) * HIDN + k0 + c8]);
        __syncthreads();

#pragma unroll
        for (int ks = 0; ks < 2; ks++) {
            const int cq8 = (ks * 4 + quad) * 8;
            short8 a[4], b[2];
#pragma unroll
            for (int i = 0; i < 4; i++)
                a[i] = *(const short8*)&Als[wm + i*16 + l16][cq8];
#pragma unroll
            for (int j = 0; j < 2; j++)
                b[j] = *(const short8*)&Bls[wn + j*16 + l16][cq8];
#pragma unroll
            for (int i = 0; i < 4; i++)
#pragma unroll
                for (int j = 0; j < 2; j++)
                    acc[i][j] = mfma_s(a[i], b[j], acc[i][j]);
        }
    }

#pragma unroll
    for (int i = 0; i < 4; i++)
#pragma unroll
        for (int j = 0; j < 2; j++)
#pragma unroll
            for (int r = 0; r < 4; r++) {
                int m = m0 + wm + i*16 + quad*4 + r;
                int n = n0 + wn + j*16 + l16;
                C[m * HIDN + n] = acc[i][j][r];
            }
}

// ---------------------------------------------------------------------------
// Flash attention (round-4 version VERBATIM, 48 us proven).
// Transposed orientation: S^T = K·Q^T; O^T = V^T·P^T. XOR-swizzled LDS;
// P overlays K region (32 KB -> 5 blk/CU LDS-wise).
// ---------------------------------------------------------------------------
__global__ __launch_bounds__(256, 4) void attn_kernel(const short* __restrict__ Qh,
                                                      const short* __restrict__ Kh,
                                                      const short* __restrict__ VT,
                                                      const int* __restrict__ vlen,
                                                      short* __restrict__ AO) {
    __shared__ __align__(16) short Ksh[128 * 64];   // K tile; overlaid by P
    __shared__ __align__(16) short Vsh[64 * 128];   // V^T tile
    short* Psh = Ksh;                                // wave w region: w*2048 shorts

    const int t = threadIdx.x, w = t >> 6, lane = t & 63;
    const int quad = lane >> 4, l16 = lane & 15;
    const int qb = blockIdx.x * 64;
    const int h = blockIdx.y, b = blockIdx.z;
    const int bh = b * NH + h;
    const int vl = vlen[b];
    const int nfull = vl >> 7, rem = vl & 127;
    const int nt = nfull + (rem ? 1 : 0);

    const float SC = 0.180336879f;                   // 0.125 * log2(e)

    const short* qrow = &Qh[(bh * S_ + qb + w * 16 + l16) * DH];
    short8 qa0 = *(const short8*)&qrow[quad * 8];
    short8 qa1 = *(const short8*)&qrow[32 + quad * 8];

    float m_run = -1e30f, l_run = 0.f;
    floatx4 Oacc[4];
    floatx4 zero = {0.f, 0.f, 0.f, 0.f};
#pragma unroll
    for (int dt = 0; dt < 4; dt++) Oacc[dt] = zero;

    for (int kt = 0; kt < nt; kt++) {
        const int base = kt << 7;
        const bool bnd = (base + 128) > vl;
        __syncthreads();                             // prev PV reads done
        {
            const short* Kg = &Kh[(bh * S_ + base) * DH];
#pragma unroll
            for (int it = 0; it < 4; it++) {
                int idx = it * 256 + t;
                int row = idx >> 3, c = idx & 7;
                *(short8*)&Ksh[row * 64 + (((c ^ (row & 7))) << 3)] =
                    *(const short8*)&Kg[row * DH + (c << 3)];
            }
            const short* Vg = &VT[bh * DH * S_ + base];
#pragma unroll
            for (int it = 0; it < 4; it++) {
                int idx = it * 256 + t;
                int d = idx >> 4, c = idx & 15;
                *(short8*)&Vsh[d * 128 + (((c ^ (d & 7))) << 3)] =
                    *(const short8*)&Vg[d * S_ + (c << 3)];
            }
        }
        __syncthreads();                             // staging visible

        // S^T: rows = key, col = q (l16)
        floatx4 sc[8];
#pragma unroll
        for (int n = 0; n < 8; n++) {
            int krow = n * 16 + l16;
            const short* kr = &Ksh[krow * 64];
            short8 kb0 = *(const short8*)&kr[((quad ^ (krow & 7)) << 3)];
            short8 kb1 = *(const short8*)&kr[(((4 + quad) ^ (krow & 7)) << 3)];
            floatx4 s = zero;
            s = mfma_s(kb0, qa0, s);
            s = mfma_s(kb1, qa1, s);
            sc[n] = s;
        }
        __syncthreads();                             // all Ksh reads done (P overlay)

        if (!bnd) {
#pragma unroll
            for (int n = 0; n < 8; n++)
#pragma unroll
                for (int r = 0; r < 4; r++) sc[n][r] *= SC;
        } else {
#pragma unroll
            for (int n = 0; n < 8; n++)
#pragma unroll
                for (int r = 0; r < 4; r++) {
                    int key = base + n * 16 + quad * 4 + r;
                    sc[n][r] = (key < vl) ? sc[n][r] * SC : -1e30f;
                }
        }

        // softmax (exp2 domain), per-lane q-column + 2 shuffles
        float mx = vmax4(sc[0]);
#pragma unroll
        for (int n = 1; n < 8; n++) mx = fmaxf(mx, vmax4(sc[n]));
        mx = fmaxf(mx, __shfl_xor(mx, 16));
        mx = fmaxf(mx, __shfl_xor(mx, 32));
        float mnew = fmaxf(m_run, mx);
        float alpha = __builtin_amdgcn_exp2f(m_run - mnew);
        m_run = mnew;
        float rs = 0.f;
#pragma unroll
        for (int n = 0; n < 8; n++)
#pragma unroll
            for (int r = 0; r < 4; r++) {
                float p = __builtin_amdgcn_exp2f(sc[n][r] - mnew);
                sc[n][r] = p;
                rs += p;
            }
        rs += __shfl_xor(rs, 16);
        rs += __shfl_xor(rs, 32);
        l_run = l_run * alpha + rs;
#pragma unroll
        for (int dt = 0; dt < 4; dt++)
#pragma unroll
            for (int r = 0; r < 4; r++) Oacc[dt][r] *= alpha;   // alpha lane-uniform

        // P^T store: 4 register-rows = 4 consecutive keys -> b64 writes
#pragma unroll
        for (int n = 0; n < 8; n++) {
            unsigned lo = pack2(sc[n][0], sc[n][1]);
            unsigned hi = pack2(sc[n][2], sc[n][3]);
            int c = (n << 1) + (quad >> 1);
            int idx = (w << 11) + (l16 << 7) + ((c ^ (l16 & 7)) << 3) + ((quad & 1) << 2);
            uint2v pv; pv[0] = lo; pv[1] = hi;
            *(uint2v*)&Psh[idx] = pv;
        }
        __syncthreads();                             // P visible + ordered

        // O^T += V^T * P^T
#pragma unroll
        for (int kk = 0; kk < 4; kk++) {
            int pc = (kk << 2) + quad;
            short8 pf = *(const short8*)&Psh[(w << 11) + (l16 << 7) + ((pc ^ (l16 & 7)) << 3)];
#pragma unroll
            for (int dt = 0; dt < 4; dt++) {
                int vrow = dt * 16 + l16;
                short8 vf = *(const short8*)&Vsh[vrow * 128 + ((pc ^ (vrow & 7)) << 3)];
                Oacc[dt] = mfma_s(vf, pf, Oacc[dt]);
            }
        }
    }

    // epilogue
    float inv = 1.0f / l_run;
    int q = qb + w * 16 + l16;
    short* dst = &AO[(b * S_ + q) * HIDN + h * DH];
#pragma unroll
    for (int dt = 0; dt < 4; dt++) {
        uint2v v;
        v[0] = pack2(Oacc[dt][0] * inv, Oacc[dt][1] * inv);
        v[1] = pack2(Oacc[dt][2] * inv, Oacc[dt][3] * inv);
        *(uint2v*)&dst[dt * 16 + quad * 4] = v;
    }
}

extern "C" void kernel_launch(void* const* d_in, const int* in_sizes, int n_in,
                              void* d_out, int out_size, void* d_ws, size_t ws_size,
                              hipStream_t stream) {
    const float* q  = (const float*)d_in[0];
    const float* k  = (const float*)d_in[1];
    const float* v  = (const float*)d_in[2];
    const int*   vl = (const int*)d_in[3];
    const float* wq = (const float*)d_in[4];
    const float* wk = (const float*)d_in[5];
    const float* wv = (const float*)d_in[6];
    const float* wo = (const float*)d_in[7];
    float* out = (float*)d_out;

    const size_t HSZ = (size_t)B_ * NH * S_ * DH;  // 4.19M shorts
    short* Qh  = (short*)d_ws;
    short* Kh  = Qh + HSZ;
    short* VT  = Kh + HSZ;
    short* AO  = VT + HSZ;
    short* Wqkv = AO;   // 3*256K shorts in the AO region (dead until attn)

    dim3 blk(256);
    cvt_w<<<dim3(256, 3), blk, 0, stream>>>(wq, wk, wv, Wqkv);
    gemm_qkv<<<dim3(64, 4, 3), blk, 0, stream>>>(q, k, v, Wqkv, Qh, Kh, VT);
    attn_kernel<<<dim3(S_ / 64, NH, B_), blk, 0, stream>>>(Qh, Kh, VT, vl, AO);
    gemm_out<<<dim3(64, 8), blk, 0, stream>>>(AO, wo, out);
}